// Round 12
// baseline (223.569 us; speedup 1.0000x reference)
//
#include <hip/hip_runtime.h>

// BitDelta chained layers: per layer W = base + bd*mask (4096x4096 fp32),
// x = x @ W, x [16,4096].  Weight-streaming, memory-bound (134 MB/layer).
//
// R12: WAVES-SPLIT-COLUMNS register version (T1 probe: 4 KB DRAM runs).
// Block = 256 thr / 4 waves; tile = KC=32 k-rows x CT=1024 cols; wave w
// owns cols w*256..+255 (lane: 4 cols, acc[16][4]).  The 4 waves' same-row
// loads form 4 ADJACENT 1 KB islands = 4 KB dense runs (vs R10's isolated
// 1 KB islands 16 KB apart).  Each wave covers all 32 rows -> NO inter-wave
// reduce, NO LDS, NO barriers; epilogue = 16 direct float4 stores.
// Grid = 128 kchunks x 4 cchunks = 512 (2 blocks/CU, 8 waves/CU).
// Partials: 128 slabs = 32 MB (L3-resident).  Depth-1 window prefetch and
// wave-uniform scalar-x exactly as R10.
// Stage 2: 256 blocks x 64 threads fold 128 slabs.

#define DD 4096
#define BB 16
#define KC 32                  // k-rows per block (= per wave)
#define CT 1024                // cols per block (4 waves x 256)
#define VEC 4
#define TPB 256
#define KCHUNKS (DD / KC)      // 128
#define NCHUNKS (DD / CT)      // 4
#define OUT_ELEMS (BB * DD)    // 65536

typedef float f32x4 __attribute__((ext_vector_type(4)));

__global__ __launch_bounds__(TPB)
void bitdelta_layer(const float* __restrict__ x,
                    const float* __restrict__ base,
                    const float* __restrict__ mask,
                    const float* __restrict__ bitdelta,
                    int layer,
                    float* __restrict__ part) {
    const int tid = threadIdx.x;
    const int l   = tid & 63;
    const int wid = __builtin_amdgcn_readfirstlane(tid >> 6);  // 0..3

    const int bid    = blockIdx.x;
    const int cchunk = bid & (NCHUNKS - 1);
    const int kchunk = bid >> 2;              // 0..127

    const int c0 = cchunk * CT + wid * 256 + l * VEC;
    const int k0 = kchunk * KC;               // block-uniform

    const float bd = bitdelta[layer];

    const float* wb = base + (size_t)k0 * DD + c0;
    const float* wm = mask + (size_t)k0 * DD + c0;
    const float* xp = x + k0;                 // block-uniform -> s_load

    float acc[BB][VEC];
#pragma unroll
    for (int r = 0; r < BB; ++r)
#pragma unroll
        for (int c = 0; c < VEC; ++c) acc[r][c] = 0.0f;

    // Window 0 (2 k-rows): float4 loads; 4 waves' same-row loads are
    // adjacent 1 KB islands -> 4 KB dense run per row per stream.
    float4 b0 = *reinterpret_cast<const float4*>(wb);
    float4 b1 = *reinterpret_cast<const float4*>(wb + DD);
    float4 m0 = *reinterpret_cast<const float4*>(wm);
    float4 m1 = *reinterpret_cast<const float4*>(wm + DD);

#pragma unroll
    for (int kw = 0; kw < KC; kw += 2) {
        float4 nb0, nb1, nm0, nm1;
        if (kw + 2 < KC) {   // compile-time after full unroll
            const float* pb = wb + (size_t)(kw + 2) * DD;
            const float* pm = wm + (size_t)(kw + 2) * DD;
            nb0 = *reinterpret_cast<const float4*>(pb);
            nb1 = *reinterpret_cast<const float4*>(pb + DD);
            nm0 = *reinterpret_cast<const float4*>(pm);
            nm1 = *reinterpret_cast<const float4*>(pm + DD);
        }

        const float w00 = fmaf(bd, m0.x, b0.x);
        const float w01 = fmaf(bd, m0.y, b0.y);
        const float w02 = fmaf(bd, m0.z, b0.z);
        const float w03 = fmaf(bd, m0.w, b0.w);
        const float w10 = fmaf(bd, m1.x, b1.x);
        const float w11 = fmaf(bd, m1.y, b1.y);
        const float w12 = fmaf(bd, m1.z, b1.z);
        const float w13 = fmaf(bd, m1.w, b1.w);

#pragma unroll
        for (int r = 0; r < BB; ++r) {
            // Block-uniform -> scalar loads on the SMEM pipe.
            const float xv0 = xp[r * DD + kw];
            const float xv1 = xp[r * DD + kw + 1];
            acc[r][0] = fmaf(xv0, w00, acc[r][0]);
            acc[r][1] = fmaf(xv0, w01, acc[r][1]);
            acc[r][2] = fmaf(xv0, w02, acc[r][2]);
            acc[r][3] = fmaf(xv0, w03, acc[r][3]);
            acc[r][0] = fmaf(xv1, w10, acc[r][0]);
            acc[r][1] = fmaf(xv1, w11, acc[r][1]);
            acc[r][2] = fmaf(xv1, w12, acc[r][2]);
            acc[r][3] = fmaf(xv1, w13, acc[r][3]);
        }

        if (kw + 2 < KC) { b0 = nb0; b1 = nb1; m0 = nm0; m1 = nm1; }
    }

    // Epilogue: direct partial store (no reduce, no barriers, no LDS).
    float* pp = part + (size_t)kchunk * OUT_ELEMS + c0;
#pragma unroll
    for (int r = 0; r < BB; ++r) {
        f32x4 v = { acc[r][0], acc[r][1], acc[r][2], acc[r][3] };
        *reinterpret_cast<f32x4*>(pp + (size_t)r * DD) = v;
    }
}

// Stage 2: out[e] = sum_k part[k][e].  256 blocks x 64 threads: one wave
// per CU; lane owns one float4 (1 KB contiguous per slab-load); 128
// independent slab loads per thread (deep ILP, mostly L3 hits).
__global__ __launch_bounds__(64)
void reduce_partials(const float* __restrict__ part, float* __restrict__ out) {
    const int idx = (blockIdx.x * 64 + threadIdx.x) * 4;   // float4 base
    f32x4 a = *reinterpret_cast<const f32x4*>(&part[idx]);
#pragma unroll 8
    for (int k = 1; k < KCHUNKS; ++k) {
        const f32x4 p = *reinterpret_cast<const f32x4*>(
            &part[(size_t)k * OUT_ELEMS + idx]);
        a += p;
    }
    *reinterpret_cast<f32x4*>(&out[idx]) = a;
}

extern "C" void kernel_launch(void* const* d_in, const int* in_sizes, int n_in,
                              void* d_out, int out_size, void* d_ws, size_t ws_size,
                              hipStream_t stream) {
    const float* x    = (const float*)d_in[0];   // [16,4096]
    const float* base = (const float*)d_in[1];   // [4,4096,4096]
    const float* mask = (const float*)d_in[2];   // [4,4096,4096]
    const float* bd   = (const float*)d_in[3];   // [4]
    float* out = (float*)d_out;                  // [16,4096] fp32

    float* part = (float*)d_ws;                  // 128 x 65536 floats = 32 MB
    float* y0   = part + (size_t)KCHUNKS * OUT_ELEMS;
    float* y1   = y0 + OUT_ELEMS;

    const size_t layer_stride = (size_t)DD * DD;
    const int    grid1 = KCHUNKS * NCHUNKS;      // 512
    const int    grid2 = OUT_ELEMS / (64 * 4);   // 256 blocks x 64 threads

    bitdelta_layer<<<grid1, TPB, 0, stream>>>(x, base, mask, bd, 0, part);
    reduce_partials<<<grid2, 64, 0, stream>>>(part, y0);

    bitdelta_layer<<<grid1, TPB, 0, stream>>>(y0, base + 1 * layer_stride,
                                              mask + 1 * layer_stride, bd, 1, part);
    reduce_partials<<<grid2, 64, 0, stream>>>(part, y1);

    bitdelta_layer<<<grid1, TPB, 0, stream>>>(y1, base + 2 * layer_stride,
                                              mask + 2 * layer_stride, bd, 2, part);
    reduce_partials<<<grid2, 64, 0, stream>>>(part, y0);

    bitdelta_layer<<<grid1, TPB, 0, stream>>>(y0, base + 3 * layer_stride,
                                              mask + 3 * layer_stride, bd, 3, part);
    reduce_partials<<<grid2, 64, 0, stream>>>(part, out);
}

// Round 13
// 152.960 us; speedup vs baseline: 1.4616x; 1.4616x over previous
//
#include <hip/hip_runtime.h>

// BitDelta chained layers: per layer W = base + bd*mask (4096x4096 fp32),
// x = x @ W, x [16,4096].  Weight-streaming, memory-bound (134 MB/layer).
//
// R13 = R10 EXACTLY except ONE change (clean A/B): x is staged once into
// LDS (16x64 slice = 4 KB, one float4 per thread + 1 barrier) and the
// k-loop reads it via broadcast ds_read (adjacent pairs -> b64) instead of
// per-window scalar s_loads.  Tests the hypothesis that batched s_load
// lgkm-waits (~200 cy L2-hit each, SGPR-pressure-limited depth) serialize
// the streaming window (28.6 us = 4.7 TB/s vs 6.3 achievable).
//
// Stage 1: grid 1024 = (KCHUNKS=64) x (NCHUNKS=16), TPB=256 (4 waves),
// 4 blocks/CU.  Wave owns KW=16 k-rows; lane owns 4 cols (float4 granule,
// depth-1 window prefetch).  4-wave LDS tree-reduce (12 KB); wave 0
// writes the block partial.  Stage 2: 256 blocks x 64 threads.

#define DD 4096
#define BB 16
#define KW 16                  // k-rows per wave
#define NW 4                   // waves per block
#define KC (KW * NW)           // 64 k-rows per block
#define VEC 4
#define CT 256                 // cols per block (64 lanes * 4)
#define TPB 256
#define KCHUNKS (DD / KC)      // 64
#define NCHUNKS (DD / CT)      // 16
#define OUT_ELEMS (BB * DD)    // 65536

typedef float f32x4 __attribute__((ext_vector_type(4)));

__global__ __launch_bounds__(TPB)
void bitdelta_layer(const float* __restrict__ x,
                    const float* __restrict__ base,
                    const float* __restrict__ mask,
                    const float* __restrict__ bitdelta,
                    int layer,
                    float* __restrict__ part) {
    __shared__ float red[16][3 * 64];   // 12 KB reduce buffer
    __shared__ float xs[BB][KC];        // 4 KB x slice [16][64]

    const int tid = threadIdx.x;
    const int l   = tid & 63;
    const int wid = __builtin_amdgcn_readfirstlane(tid >> 6);  // wave-uniform

    const int bid    = blockIdx.x;
    const int cchunk = bid & (NCHUNKS - 1);
    const int kchunk = bid >> 4;              // bid / NCHUNKS

    const int c0    = cchunk * CT + l * VEC;
    const int k0blk = kchunk * KC;
    const int k0    = k0blk + wid * KW;       // wave-uniform

    const float bd = bitdelta[layer];

    // ---- ONE-SHOT x staging: 16 rows x 64 cols, one float4/thread ----
    {
        const int r  = tid >> 4;              // 0..15
        const int cc = (tid & 15) * 4;        // 0..60
        *reinterpret_cast<float4*>(&xs[r][cc]) =
            *reinterpret_cast<const float4*>(&x[r * DD + k0blk + cc]);
    }
    __syncthreads();

    const float* wb = base + (size_t)k0 * DD + c0;
    const float* wm = mask + (size_t)k0 * DD + c0;
    const int xbase = wid * KW;               // wave-uniform col offset in xs

    float acc[BB][VEC];
#pragma unroll
    for (int r = 0; r < BB; ++r)
#pragma unroll
        for (int c = 0; c < VEC; ++c) acc[r][c] = 0.0f;

    // Window 0 (2 k-rows): float4 loads = 1 KB/wave-instruction.
    float4 b0 = *reinterpret_cast<const float4*>(wb);
    float4 b1 = *reinterpret_cast<const float4*>(wb + DD);
    float4 m0 = *reinterpret_cast<const float4*>(wm);
    float4 m1 = *reinterpret_cast<const float4*>(wm + DD);

#pragma unroll
    for (int kw = 0; kw < KW; kw += 2) {
        float4 nb0, nb1, nm0, nm1;
        if (kw + 2 < KW) {   // compile-time after full unroll
            const float* pb = wb + (size_t)(kw + 2) * DD;
            const float* pm = wm + (size_t)(kw + 2) * DD;
            nb0 = *reinterpret_cast<const float4*>(pb);
            nb1 = *reinterpret_cast<const float4*>(pb + DD);
            nm0 = *reinterpret_cast<const float4*>(pm);
            nm1 = *reinterpret_cast<const float4*>(pm + DD);
        }

        const float w00 = fmaf(bd, m0.x, b0.x);
        const float w01 = fmaf(bd, m0.y, b0.y);
        const float w02 = fmaf(bd, m0.z, b0.z);
        const float w03 = fmaf(bd, m0.w, b0.w);
        const float w10 = fmaf(bd, m1.x, b1.x);
        const float w11 = fmaf(bd, m1.y, b1.y);
        const float w12 = fmaf(bd, m1.z, b1.z);
        const float w13 = fmaf(bd, m1.w, b1.w);

#pragma unroll
        for (int r = 0; r < BB; ++r) {
            // Broadcast LDS reads (adjacent pair -> ds_read_b64), no bank
            // conflicts (all lanes same address).
            const float xv0 = xs[r][xbase + kw];
            const float xv1 = xs[r][xbase + kw + 1];
            acc[r][0] = fmaf(xv0, w00, acc[r][0]);
            acc[r][1] = fmaf(xv0, w01, acc[r][1]);
            acc[r][2] = fmaf(xv0, w02, acc[r][2]);
            acc[r][3] = fmaf(xv0, w03, acc[r][3]);
            acc[r][0] = fmaf(xv1, w10, acc[r][0]);
            acc[r][1] = fmaf(xv1, w11, acc[r][1]);
            acc[r][2] = fmaf(xv1, w12, acc[r][2]);
            acc[r][3] = fmaf(xv1, w13, acc[r][3]);
        }

        if (kw + 2 < KW) { b0 = nb0; b1 = nb1; m0 = nm0; m1 = nm1; }
    }

    // 4-wave LDS reduce, four rounds of 16 elements (12 KB, conflict-free).
#pragma unroll
    for (int t = 0; t < 4; ++t) {
        __syncthreads();
        if (wid != 0) {
#pragma unroll
            for (int e = 0; e < 16; ++e) {
                const int r = t * 4 + (e >> 2), c = e & 3;
                red[e][(wid - 1) * 64 + l] = acc[r][c];
            }
        }
        __syncthreads();
        if (wid == 0) {
#pragma unroll
            for (int e = 0; e < 16; ++e) {
                const int r = t * 4 + (e >> 2), c = e & 3;
                acc[r][c] += red[e][l] + red[e][64 + l] + red[e][128 + l];
            }
        }
    }

    // Wave 0 writes the block partial: [16][256] slab, float4 stores.
    if (wid == 0) {
        float* pp = part + (size_t)kchunk * OUT_ELEMS;
#pragma unroll
        for (int r = 0; r < BB; ++r) {
            const float4 v = make_float4(acc[r][0], acc[r][1], acc[r][2], acc[r][3]);
            *reinterpret_cast<float4*>(&pp[r * DD + c0]) = v;
        }
    }
}

// Stage 2: out[e] = sum_k part[k][e].  256 blocks x 64 threads: one wave
// per CU; lane owns one float4 (1 KB contiguous per slab-load); 64
// independent slab loads per thread (deep ILP).
__global__ __launch_bounds__(64)
void reduce_partials(const float* __restrict__ part, float* __restrict__ out) {
    const int idx = (blockIdx.x * 64 + threadIdx.x) * 4;   // float4 base
    f32x4 a = *reinterpret_cast<const f32x4*>(&part[idx]);
#pragma unroll
    for (int k = 1; k < KCHUNKS; ++k) {
        const f32x4 p = *reinterpret_cast<const f32x4*>(
            &part[(size_t)k * OUT_ELEMS + idx]);
        a += p;
    }
    *reinterpret_cast<f32x4*>(&out[idx]) = a;
}

extern "C" void kernel_launch(void* const* d_in, const int* in_sizes, int n_in,
                              void* d_out, int out_size, void* d_ws, size_t ws_size,
                              hipStream_t stream) {
    const float* x    = (const float*)d_in[0];   // [16,4096]
    const float* base = (const float*)d_in[1];   // [4,4096,4096]
    const float* mask = (const float*)d_in[2];   // [4,4096,4096]
    const float* bd   = (const float*)d_in[3];   // [4]
    float* out = (float*)d_out;                  // [16,4096] fp32

    float* part = (float*)d_ws;                  // 64 x 65536 floats = 16 MB
    float* y0   = part + (size_t)KCHUNKS * OUT_ELEMS;
    float* y1   = y0 + OUT_ELEMS;

    const size_t layer_stride = (size_t)DD * DD;
    const int    grid1 = KCHUNKS * NCHUNKS;      // 1024
    const int    grid2 = OUT_ELEMS / (64 * 4);   // 256 blocks, 64 threads

    bitdelta_layer<<<grid1, TPB, 0, stream>>>(x, base, mask, bd, 0, part);
    reduce_partials<<<grid2, 64, 0, stream>>>(part, y0);

    bitdelta_layer<<<grid1, TPB, 0, stream>>>(y0, base + 1 * layer_stride,
                                              mask + 1 * layer_stride, bd, 1, part);
    reduce_partials<<<grid2, 64, 0, stream>>>(part, y1);

    bitdelta_layer<<<grid1, TPB, 0, stream>>>(y1, base + 2 * layer_stride,
                                              mask + 2 * layer_stride, bd, 2, part);
    reduce_partials<<<grid2, 64, 0, stream>>>(part, y0);

    bitdelta_layer<<<grid1, TPB, 0, stream>>>(y0, base + 3 * layer_stride,
                                              mask + 3 * layer_stride, bd, 3, part);
    reduce_partials<<<grid2, 64, 0, stream>>>(part, out);
}